// Round 10
// baseline (33.730 us; speedup 1.0000x reference)
//
#include <hip/hip_runtime.h>
#include <math.h>

#define LL 4096
#define BB 2048
#define NSEG 8                 // segments per row
#define SEGLEN 512             // elements per segment (64 lanes x 8)
#define NT 256                 // 4 independent waves per block
#define WPB 4
#define ALPHA 1.0f
#define BETA 0.5f
#define NEG_INF (-__builtin_inff())
#define POS_INF (__builtin_inff())

// Per-wave LDS slice: 70 chunks (rel -3..66) x 9 dwords (8 elems + 1 pad).
// Own-chunk base = 9*(lane+3); element at logical delta d lives at
// base + 9*(d>>3) + (d&7)  (arith shift) -> compile-time immediates.
#define CBUF 630
#define OFS2(d) (9 * ((d) >> 3) + ((d) & 7))

// ---- DPP wave64 sum reduction (VALU pipe, no LDS) ----
template <int CTRL, int RM>
__device__ __forceinline__ float dpp_addf(float v) {
    int s = __builtin_amdgcn_update_dpp(0, __float_as_int(v), CTRL, RM, 0xf, true);
    return v + __int_as_float(s);
}
__device__ __forceinline__ float wredf(float v) {
    v = dpp_addf<0x111, 0xf>(v);   // row_shr:1
    v = dpp_addf<0x112, 0xf>(v);   // row_shr:2
    v = dpp_addf<0x114, 0xf>(v);   // row_shr:4
    v = dpp_addf<0x118, 0xf>(v);   // row_shr:8
    v = dpp_addf<0x142, 0xa>(v);   // row_bcast:15
    v = dpp_addf<0x143, 0xc>(v);   // row_bcast:31
    return v;                      // total in lane 63
}

// Intra-wave LDS ordering: producer and consumer are the same wave, so a
// ds-complete wait is sufficient (no s_barrier, no vmcnt drain).
__device__ __forceinline__ void wave_sync() {
    asm volatile("s_waitcnt lgkmcnt(0)" ::: "memory");
}

__device__ __forceinline__ float scan_store(const float (&x)[8], float* S, float* P) {
    float pp[8], ss[8];
    pp[0] = x[0];
#pragma unroll
    for (int j = 1; j < 8; ++j) pp[j] = fmaxf(pp[j - 1], x[j]);
    ss[7] = x[7];
#pragma unroll
    for (int j = 6; j >= 0; --j) ss[j] = fmaxf(ss[j + 1], x[j]);
#pragma unroll
    for (int j = 0; j < 8; ++j) { P[j] = pp[j]; S[j] = ss[j]; }
    return pp[7];
}

__global__ __launch_bounds__(NT, 6) void seg_kernel(const float* __restrict__ gA,
                                                    const float* __restrict__ gB,
                                                    float4* __restrict__ ws4) {
    __shared__ float sS[WPB * CBUF];   // per-wave private slices
    __shared__ float sP[WPB * CBUF];

    const int t = threadIdx.x;
    const int w = t >> 6, lane = t & 63;
    const int gseg = blockIdx.x * WPB + w;
    const int row = gseg >> 3, seg = gseg & 7;

    const float* baseA = gA + (size_t)row * LL + seg * SEGLEN;
    const float* baseB = gB + (size_t)row * LL + seg * SEGLEN;

    float* const Sw = sS + w * CBUF;
    float* const Pw = sP + w * CBUF;
    float* const Sb = Sw + 9 * (lane + 3);   // own-chunk base
    float* const Pb = Pw + 9 * (lane + 3);

    // ---- issue all loads: own chunk (2x f4 per signal) + halo (lanes 0..5) ----
    const float4* a4 = (const float4*)baseA;
    const float4* b4 = (const float4*)baseB;
    float4 va0 = a4[2 * lane], va1 = a4[2 * lane + 1];
    float4 vb0 = b4[2 * lane], vb1 = b4[2 * lane + 1];

    const int hc = (lane < 3) ? (lane - 3) : (61 + lane);   // rel chunks -3..-1, 64..66
    const bool hlane = (lane < 6);                          // ONLY lanes 0..5 own a halo chunk
    const bool hvalid = hlane && ((unsigned)(seg * 64 + hc) < 512u);
    float4 ha0, ha1, hb0, hb1;
    if (hvalid) {
        const float4* ah = (const float4*)(baseA + hc * 8);
        const float4* bh = (const float4*)(baseB + hc * 8);
        ha0 = ah[0]; ha1 = ah[1];
        hb0 = bh[0]; hb1 = bh[1];
    }

    float xA[8], xB[8];
    xA[0] = va0.x; xA[1] = va0.y; xA[2] = va0.z; xA[3] = va0.w;
    xA[4] = va1.x; xA[5] = va1.y; xA[6] = va1.z; xA[7] = va1.w;
    xB[0] = vb0.x; xB[1] = vb0.y; xB[2] = vb0.z; xB[3] = vb0.w;
    xB[4] = vb1.x; xB[5] = vb1.y; xB[6] = vb1.z; xB[7] = vb1.w;

    // ---- fused stats over own 512 elems (each element counted once) ----
    float se = 0.f, dtp = 0.f, na = 0.f, nb = 0.f;
#pragma unroll
    for (int j = 0; j < 8; ++j) {
        float d = xA[j] - xB[j];
        se  += d * d;
        dtp += xA[j] * xB[j];
        na  += xA[j] * xA[j];
        nb  += xB[j] * xB[j];
    }

    // Halo store: ONLY lanes 0..5 (hc is meaningless for lanes >= 6; unguarded
    // stores would land 9*(hc+3) > CBUF dwords out — corrupting the next wave's
    // slice. This was R9's bug.)
    auto halo_store = [&](float4 h0, float4 h1) {
        if (!hlane) return;
        float hx[8];
        if (hvalid) {
            hx[0] = h0.x; hx[1] = h0.y; hx[2] = h0.z; hx[3] = h0.w;
            hx[4] = h1.x; hx[5] = h1.y; hx[6] = h1.z; hx[7] = h1.w;
        } else {
#pragma unroll
            for (int j = 0; j < 8; ++j) hx[j] = NEG_INF;
        }
        scan_store(hx, Sw + 9 * (hc + 3), Pw + 9 * (hc + 3));
    };

    auto evalsig = [&](const float (&x)[8], float cmax, int& cnt20, unsigned& m10) {
        const float Cm2 = Pb[OFS2(-9)];    // chunk -2 max
        const float Cm1 = Pb[OFS2(-1)];    // chunk -1 max
        const float Cp1 = Pb[OFS2(15)];    // chunk +1 max
        const float Cp2 = Pb[OFS2(23)];    // chunk +2 max
        const float f1 = fmaxf(Cm1, cmax);
        const float f2 = fmaxf(cmax, Cp1);
        const float g2 = fmaxf(f1, Cp1);
        const float g1 = fmaxf(g2, Cm2);
        const float g3 = fmaxf(g2, Cp2);
        const float xm1 = (seg == 0 && lane == 0)         ? POS_INF : Sb[OFS2(-1)];
        const float xp1 = (seg == NSEG - 1 && lane == 63) ? POS_INF : Pb[OFS2(8)];
        cnt20 = 0; m10 = 0u;
#pragma unroll
        for (int j = 0; j < 8; ++j) {
            float xi = x[j];
            float xl = (j > 0) ? x[j - 1] : xm1;
            float xr = (j < 7) ? x[j + 1] : xp1;
            bool lm = (xi > xl) && (xi > xr);
            float a19 = Sb[OFS2(j - 9)];
            float b19 = Pb[OFS2(j + 9)];
            float a39 = Sb[OFS2(j - 19)];
            float b39 = Pb[OFS2(j + 19)];
            float mid19 = (j == 0) ? f1 : ((j == 7) ? f2 : cmax);
            float mid39 = (j <= 2) ? g1 : ((j <= 4) ? g2 : g3);
            float p19 = fmaxf(fmaxf(a19, b19), mid19);
            float p39 = fmaxf(fmaxf(a39, b39), mid39);
            if (lm && xi >= p19) m10 |= (1u << j);
            if (lm && xi >= p39) cnt20++;
        }
    };

    // ---- signal A: scan -> eval (wave-private, lgkm-ordered) ----
    int cntA, cntB;
    unsigned mA, mB;
    float cmA = scan_store(xA, Sb, Pb);
    halo_store(ha0, ha1);
    wave_sync();
    evalsig(xA, cmA, cntA, mA);
    wave_sync();                       // A-reads complete before B overwrites
    // ---- signal B ----
    float cmB = scan_store(xB, Sb, Pb);
    halo_store(hb0, hb1);
    wave_sync();
    evalsig(xB, cmB, cntB, mB);

    // ---- peak-to-peak squared error (aligned positions) ----
    float p2p = 0.f;
#pragma unroll
    for (int j = 0; j < 8; ++j) {
        float av = ((mA >> j) & 1u) ? xA[j] : 0.f;
        float bv = ((mB >> j) & 1u) ? xB[j] : 0.f;
        float d = av - bv;
        p2p += d * d;
    }

    // ---- wave DPP reductions; lane 63 stores per-(row,seg) partials ----
    se = wredf(se); dtp = wredf(dtp); na = wredf(na); nb = wredf(nb);
    p2p = wredf(p2p);
    float cc = wredf((float)(cntA * 4096 + cntB));   // exact: sums << 2^24
    if (lane == 63) {
        ws4[(size_t)(seg * 2 + 0) * BB + row] = make_float4(se, dtp, na, nb);
        ws4[(size_t)(seg * 2 + 1) * BB + row] = make_float4(p2p, cc, 0.f, 0.f);
    }
}

__global__ __launch_bounds__(256) void reduce_kernel(const float4* __restrict__ ws4,
                                                     float* __restrict__ out) {
    __shared__ float red[4][4];
    const int r = blockIdx.x * 256 + threadIdx.x;    // grid 8x256 -> 2048 rows
    float se = 0.f, dtp = 0.f, na = 0.f, nb = 0.f, pp = 0.f, cc = 0.f;
#pragma unroll
    for (int s = 0; s < NSEG; ++s) {
        float4 u = ws4[(size_t)(s * 2 + 0) * BB + r];
        float4 v = ws4[(size_t)(s * 2 + 1) * BB + r];
        se += u.x; dtp += u.y; na += u.z; nb += u.w;
        pp += v.x; cc += v.y;
    }
    int packed = (int)cc;
    int ca = packed >> 12, cb = packed & 4095;
    float mse_i = se * (1.0f / LL);
    float cos_i = dtp / (sqrtf(na) * sqrtf(nb));
    float p2p_i = pp * (1.0f / LL);
    float custom_i = (ca != cb) ? (mse_i * ALPHA) : (p2p_i * BETA);
    const float invB = 1.0f / (float)BB;
    float v0 = mse_i * invB + custom_i;   // -> total_loss
    float v1 = cos_i * invB;              // -> mean cosine
    float v2 = p2p_i;                     // -> p2p_loss
    float v3 = mse_i * invB;              // -> mse_loss
    v0 = wredf(v0); v1 = wredf(v1); v2 = wredf(v2); v3 = wredf(v3);
    int w = threadIdx.x >> 6, lane = threadIdx.x & 63;
    if (lane == 63) { red[w][0] = v0; red[w][1] = v1; red[w][2] = v2; red[w][3] = v3; }
    __syncthreads();
    if (threadIdx.x == 0) {
        float a0 = 0, a1 = 0, a2 = 0, a3 = 0;
#pragma unroll
        for (int i = 0; i < 4; ++i) {
            a0 += red[i][0]; a1 += red[i][1]; a2 += red[i][2]; a3 += red[i][3];
        }
        atomicAdd(out + 0, a0);   // 8 blocks x 4 adds total — negligible contention
        atomicAdd(out + 1, a1);
        atomicAdd(out + 2, a2);
        atomicAdd(out + 3, a3);
    }
}

extern "C" void kernel_launch(void* const* d_in, const int* in_sizes, int n_in,
                              void* d_out, int out_size, void* d_ws, size_t ws_size,
                              hipStream_t stream) {
    const float* inA = (const float*)d_in[0];   // in_signal
    const float* inB = (const float*)d_in[1];   // ref_signal
    float* out = (float*)d_out;
    float4* ws4 = (float4*)d_ws;                // 16 x 2048 x 16 B = 512 KiB partials

    hipMemsetAsync(out, 0, out_size * sizeof(float), stream);
    hipLaunchKernelGGL(seg_kernel, dim3(BB * NSEG / WPB), dim3(NT), 0, stream, inA, inB, ws4);
    hipLaunchKernelGGL(reduce_kernel, dim3(NSEG), dim3(256), 0, stream, ws4, out);
}

// Round 11
// 31.350 us; speedup vs baseline: 1.0759x; 1.0759x over previous
//
#include <hip/hip_runtime.h>
#include <math.h>

#define LL 4096
#define BB 2048
#define NT 512
#define CH 8                      // contiguous elements per thread; NT*CH == LL
#define ALPHA 1.0f
#define BETA 0.5f
#define NEG_INF (-__builtin_inff())
#define POS_INF (__builtin_inff())

// Padded LDS layout: logical position i in [-24, LL+23] lives at i + (i>>3) + 27.
// IDX(8t + d) == 9t + (d + (d>>3) + 27) -> with base = arr + 9t, every offset the
// eval needs is a compile-time immediate; lane stride 9 dwords (odd) => max 2-way
// bank alias (free).
#define SPSZ 4672                 // > IDX(LL+23) = 4660
#define OFS(d) ((d) + ((d) >> 3) + 27)

// ---- DPP wave64 sum reduction (VALU pipe, no LDS/bpermute) ----
template <int CTRL, int RM>
__device__ __forceinline__ float dpp_addf(float v) {
    int s = __builtin_amdgcn_update_dpp(0, __float_as_int(v), CTRL, RM, 0xf, true);
    return v + __int_as_float(s);
}
__device__ __forceinline__ float wredf(float v) {
    v = dpp_addf<0x111, 0xf>(v);   // row_shr:1
    v = dpp_addf<0x112, 0xf>(v);   // row_shr:2
    v = dpp_addf<0x114, 0xf>(v);   // row_shr:4
    v = dpp_addf<0x118, 0xf>(v);   // row_shr:8
    v = dpp_addf<0x142, 0xa>(v);   // row_bcast:15
    v = dpp_addf<0x143, 0xc>(v);   // row_bcast:31
    return v;                      // total in lane 63
}

__global__ __launch_bounds__(NT, 4) void row_kernel(const float* __restrict__ gA,
                                                    const float* __restrict__ gB,
                                                    float4* __restrict__ ws4) {
    // One S/P pair PER SIGNAL -> both scans complete before ONE barrier,
    // both evals after it. 74.8 KB -> 2 blocks/CU.
    __shared__ float sSA[SPSZ], sPA[SPSZ];
    __shared__ float sSB[SPSZ], sPB[SPSZ];

    const int b = blockIdx.x;
    const int t = threadIdx.x;
    const float* rowA = gA + (size_t)b * LL;
    const float* rowB = gB + (size_t)b * LL;

    // ---- load both chunks straight to registers (32 B contiguous per thread) ----
    float xA[CH], xB[CH];
    {
        const float4* a4 = (const float4*)rowA;
        const float4* b4 = (const float4*)rowB;
#pragma unroll
        for (int k = 0; k < CH / 4; ++k) {
            float4 v = a4[2 * t + k];
            xA[4 * k + 0] = v.x; xA[4 * k + 1] = v.y; xA[4 * k + 2] = v.z; xA[4 * k + 3] = v.w;
        }
#pragma unroll
        for (int k = 0; k < CH / 4; ++k) {
            float4 v = b4[2 * t + k];
            xB[4 * k + 0] = v.x; xB[4 * k + 1] = v.y; xB[4 * k + 2] = v.z; xB[4 * k + 3] = v.w;
        }
    }

    // ---- fused row stats; reduce NOW (low pressure), hold wave partials in regs ----
    float se = 0.f, dtp = 0.f, na = 0.f, nb = 0.f;
#pragma unroll
    for (int j = 0; j < CH; ++j) {
        float d = xA[j] - xB[j];
        se  += d * d;
        dtp += xA[j] * xB[j];
        na  += xA[j] * xA[j];
        nb  += xB[j] * xB[j];
    }
    se = wredf(se); dtp = wredf(dtp); na = wredf(na); nb = wredf(nb);

    // ---- -inf margins (logical i in [-24,-1] and [LL, LL+23]) in all 4 arrays ----
    if (t < 24) {
        int i = t - 24;
        int p = i + (i >> 3) + 27;
        sSA[p] = NEG_INF; sPA[p] = NEG_INF;
        sSB[p] = NEG_INF; sPB[p] = NEG_INF;
    } else if (t >= NT - 24) {
        int i = LL + (t - (NT - 24));
        int p = i + (i >> 3) + 27;
        sSA[p] = NEG_INF; sPA[p] = NEG_INF;
        sSB[p] = NEG_INF; sPB[p] = NEG_INF;
    }

    // ---- in-register prefix/suffix scan -> LDS (per signal) ----
    auto scan = [&](const float (&x)[CH], float* S9, float* P9) {  // S9/P9 = arr + 9*t
        float pp[CH], ss[CH];
        pp[0] = x[0];
#pragma unroll
        for (int j = 1; j < CH; ++j) pp[j] = fmaxf(pp[j - 1], x[j]);
        ss[CH - 1] = x[CH - 1];
#pragma unroll
        for (int j = CH - 2; j >= 0; --j) ss[j] = fmaxf(ss[j + 1], x[j]);
#pragma unroll
        for (int j = 0; j < CH; ++j) {
            P9[j + 27] = pp[j];
            S9[j + 27] = ss[j];
        }
        return pp[CH - 1];         // chunk max
    };

    // ---- branchless eval (all compile-time LDS offsets) ----
    auto eval = [&](const float (&x)[CH], const float* S9, const float* P9,
                    float cmax, int& cnt20, unsigned& m10) {
        const float Cm2 = P9[OFS(-9)];
        const float Cm1 = P9[OFS(-1)];
        const float Cp1 = P9[OFS(15)];
        const float Cp2 = P9[OFS(23)];
        const float f1 = fmaxf(Cm1, cmax);
        const float f2 = fmaxf(cmax, Cp1);
        const float g2 = fmaxf(f1, Cp1);
        const float g1 = fmaxf(g2, Cm2);
        const float g3 = fmaxf(g2, Cp2);
        const float xm1 = (t == 0)      ? POS_INF : S9[OFS(-1)];   // x[base-1]
        const float xp1 = (t == NT - 1) ? POS_INF : P9[OFS(8)];    // x[base+8]

        cnt20 = 0; m10 = 0u;
#pragma unroll
        for (int j = 0; j < CH; ++j) {
            float xi = x[j];
            float xl = (j > 0)      ? x[j - 1] : xm1;
            float xr = (j < CH - 1) ? x[j + 1] : xp1;
            bool lm = (xi > xl) && (xi > xr);
            float a19 = S9[OFS(j - 9)];
            float b19 = P9[OFS(j + 9)];
            float a39 = S9[OFS(j - 19)];
            float b39 = P9[OFS(j + 19)];
            float mid19 = (j == 0) ? f1 : ((j == CH - 1) ? f2 : cmax);
            float mid39 = (j <= 2) ? g1 : ((j <= 4) ? g2 : g3);
            float p19 = fmaxf(fmaxf(a19, b19), mid19);
            float p39 = fmaxf(fmaxf(a39, b39), mid39);
            if (lm && xi >= p19) m10 |= (1u << j);
            if (lm && xi >= p39) cnt20++;
        }
    };

    // ---- both scans, ONE barrier, both evals ----
    float cmA = scan(xA, sSA + 9 * t, sPA + 9 * t);
    float cmB = scan(xB, sSB + 9 * t, sPB + 9 * t);
    __syncthreads();               // the only block-wide sync

    int cntA, cntB;
    unsigned mA, mB;
    eval(xA, sSA + 9 * t, sPA + 9 * t, cmA, cntA, mA);
    eval(xB, sSB + 9 * t, sPB + 9 * t, cmB, cntB, mB);

    // ---- peak-to-peak squared error (aligned positions) ----
    float p2p = 0.f;
#pragma unroll
    for (int j = 0; j < CH; ++j) {
        float av = ((mA >> j) & 1u) ? xA[j] : 0.f;
        float bv = ((mB >> j) & 1u) ? xB[j] : 0.f;
        float d = av - bv;
        p2p += d * d;
    }

    // ---- tail: 2 DPP chains; per-wave partials straight to workspace ----
    p2p = wredf(p2p);
    float cc = wredf((float)(cntA * 4096 + cntB));   // exact: sums << 2^24
    if ((t & 63) == 63) {
        const int w = t >> 6;
        ws4[(size_t)b * 16 + w * 2 + 0] = make_float4(se, dtp, na, nb);
        ws4[(size_t)b * 16 + w * 2 + 1] = make_float4(p2p, cc, 0.f, 0.f);
    }
}

__global__ __launch_bounds__(256) void reduce_kernel(const float4* __restrict__ ws4,
                                                     float* __restrict__ out) {
    __shared__ float red[4][4];
    const int r = blockIdx.x * 256 + threadIdx.x;    // 8x256 -> 2048 rows
    float s0 = 0, s1 = 0, s2 = 0, s3 = 0, s4 = 0, s5 = 0;
#pragma unroll
    for (int w = 0; w < 8; ++w) {
        float4 u = ws4[(size_t)r * 16 + w * 2 + 0];
        float4 v = ws4[(size_t)r * 16 + w * 2 + 1];
        s0 += u.x; s1 += u.y; s2 += u.z; s3 += u.w;
        s4 += v.x; s5 += v.y;
    }
    int packed = (int)s5;
    int ca = packed >> 12, cb = packed & 4095;
    float mse_i = s0 * (1.0f / LL);
    float cos_i = s1 / (sqrtf(s2) * sqrtf(s3));
    float p2p_i = s4 * (1.0f / LL);
    float custom_i = (ca != cb) ? (mse_i * ALPHA) : (p2p_i * BETA);
    const float invB = 1.0f / (float)BB;
    float v0 = mse_i * invB + custom_i;   // -> total_loss
    float v1 = cos_i * invB;              // -> mean cosine
    float v2 = p2p_i;                     // -> p2p_loss
    float v3 = mse_i * invB;              // -> mse_loss
    v0 = wredf(v0); v1 = wredf(v1); v2 = wredf(v2); v3 = wredf(v3);
    int w = threadIdx.x >> 6, lane = threadIdx.x & 63;
    if (lane == 63) { red[w][0] = v0; red[w][1] = v1; red[w][2] = v2; red[w][3] = v3; }
    __syncthreads();
    if (threadIdx.x == 0) {
        float a0 = 0, a1 = 0, a2 = 0, a3 = 0;
#pragma unroll
        for (int i = 0; i < 4; ++i) {
            a0 += red[i][0]; a1 += red[i][1]; a2 += red[i][2]; a3 += red[i][3];
        }
        atomicAdd(out + 0, a0);   // 8 blocks x 4 adds total — negligible contention
        atomicAdd(out + 1, a1);
        atomicAdd(out + 2, a2);
        atomicAdd(out + 3, a3);
    }
}

extern "C" void kernel_launch(void* const* d_in, const int* in_sizes, int n_in,
                              void* d_out, int out_size, void* d_ws, size_t ws_size,
                              hipStream_t stream) {
    const float* inA = (const float*)d_in[0];   // in_signal
    const float* inB = (const float*)d_in[1];   // ref_signal
    float* out = (float*)d_out;
    float4* ws4 = (float4*)d_ws;                // 2048 x 16 float4 = 512 KiB partials

    hipMemsetAsync(out, 0, out_size * sizeof(float), stream);
    hipLaunchKernelGGL(row_kernel, dim3(BB), dim3(NT), 0, stream, inA, inB, ws4);
    hipLaunchKernelGGL(reduce_kernel, dim3(8), dim3(256), 0, stream, ws4, out);
}